// Round 10
// baseline (568.308 us; speedup 1.0000x reference)
//
#include <hip/hip_runtime.h>
#include <hip/hip_fp16.h>
#include <math.h>

#define IN0    128
#define HEADS  4
#define CDIM   64
#define HC     256
#define SLOPE  0.2f
#define NPAD   50176   // 392*128, row padding for DMA staging
#define BK     32      // k elements per chunk (halves) = 64 B rows

typedef __attribute__((ext_vector_type(8))) _Float16 f16x8;
typedef __attribute__((ext_vector_type(4))) float f32x4;

__device__ __forceinline__ float h2f(ushort u) {
    __half h = *(const __half*)&u;
    return __half2float(h);
}
__device__ __forceinline__ ushort f2h(float f) {
    __half h = __float2half_rn(f);
    return *(ushort*)&h;
}

__device__ __forceinline__ void gl_lds16(const ushort* g, ushort* l) {
    __builtin_amdgcn_global_load_lds(
        (const __attribute__((address_space(1))) void*)g,
        (__attribute__((address_space(3))) void*)l,
        16, 0, 0);
}

// ---------------- fused prep: degree + xconv(fp16) + wconv(fp16,T) x3 ----------------

__device__ __forceinline__ void wconv_body(const float* __restrict__ W,
                                           ushort* __restrict__ Wt, int K, int b) {
    int tid = b * 256 + threadIdx.x;
    int k = tid & (K - 1);
    int n = tid >> (K == 128 ? 7 : 8);
    if (n >= HC) return;
    Wt[(size_t)n * K + k] = f2h(W[(size_t)k * HC + n]);
}

__global__ __launch_bounds__(256) void k_prep(
        const int* __restrict__ dst_rand, int E_rand, int* __restrict__ deg,
        const float* __restrict__ x0, ushort* __restrict__ X16, int totalx,
        const float* __restrict__ W0, ushort* __restrict__ Wt0,
        const float* __restrict__ W1, ushort* __restrict__ Wt1,
        const float* __restrict__ W2, ushort* __restrict__ Wt2,
        int B0, int B1) {
    int b = blockIdx.x;
    if (b < B0) {
        int i = b * 256 + threadIdx.x;
        if (i < E_rand) atomicAdd(&deg[dst_rand[i]], 1);
        return;
    }
    b -= B0;
    if (b < B1) {
        int i = b * 256 + threadIdx.x;
        if (i < totalx) X16[i] = f2h(x0[i]);
        return;
    }
    b -= B1;
    if (b < 128) { wconv_body(W0, Wt0, 128, b); return; }
    b -= 128;
    if (b < 256) { wconv_body(W1, Wt1, 256, b); return; }
    b -= 256;
    wconv_body(W2, Wt2, 256, b);
}

// ---------------- scan ----------------

__global__ __launch_bounds__(1024) void k_scan_partial(const int* __restrict__ deg, int Nn,
                                                       int* __restrict__ partial) {
    __shared__ int smem[1024];
    int tid = threadIdx.x;
    int i = blockIdx.x * 1024 + tid;
    smem[tid] = (i < Nn) ? deg[i] : 0;
    __syncthreads();
    #pragma unroll
    for (int d = 512; d >= 1; d >>= 1) {
        if (tid < d) smem[tid] += smem[tid + d];
        __syncthreads();
    }
    if (tid == 0) partial[blockIdx.x] = smem[0];
}

__global__ __launch_bounds__(1024) void k_scan_final(const int* __restrict__ deg, int Nn,
                                                     const int* __restrict__ partial, int NB,
                                                     int* __restrict__ rowptr,
                                                     int* __restrict__ cur) {
    __shared__ int smem[1024];
    __shared__ int s_off, s_total;
    int tid = threadIdx.x;
    if (tid < 64) {
        int v = (tid < NB) ? partial[tid] : 0;
        int incl = v;
        #pragma unroll
        for (int d = 1; d < 64; d <<= 1) {
            int t = __shfl_up(incl, d);
            if (tid >= d) incl += t;
        }
        if (tid == (int)blockIdx.x) s_off = incl - v;
        if (tid == 63) s_total = incl;
    }
    int i = blockIdx.x * 1024 + tid;
    int v = (i < Nn) ? deg[i] : 0;
    smem[tid] = v;
    __syncthreads();
    #pragma unroll
    for (int d = 1; d < 1024; d <<= 1) {
        int t = 0;
        if (tid >= d) t = smem[tid - d];
        __syncthreads();
        smem[tid] += t;
        __syncthreads();
    }
    if (i < Nn) {
        int e = s_off + smem[tid] - v;
        rowptr[i] = e;
        cur[i] = e;
    }
    if (blockIdx.x == 0 && tid == 0) rowptr[Nn] = s_total;
}

__global__ void k_scatter(const int* __restrict__ src, const int* __restrict__ dst, int E_rand,
                          int* __restrict__ cur, int* __restrict__ csr_src) {
    int i = blockIdx.x * blockDim.x + threadIdx.x;
    if (i < E_rand) {
        int d = dst[i];
        int p = atomicAdd(&cur[d], 1);
        csr_src[p] = src[i];
    }
}

// ---------------- fused GEMM + attention scores (fp16 MFMA, A-only LDS dbuf) ----------------

__global__ __launch_bounds__(256) void k_gemm_att(const ushort* __restrict__ X16,
                                                  const ushort* __restrict__ Wt,
                                                  const float* __restrict__ attS,
                                                  const float* __restrict__ attD,
                                                  ushort* __restrict__ H16out,
                                                  float* __restrict__ a_src_v,
                                                  float* __restrict__ a_dst_v,
                                                  int M, int K) {
    __shared__ ushort As[2][128 * BK];

    int row0 = blockIdx.x * 128;
    int col0 = blockIdx.y * 128;
    int t    = threadIdx.x;
    int wave = t >> 6, lane = t & 63;
    int wm = wave & 1, wn = wave >> 1;
    int quad = lane >> 4, l16 = lane & 15;

    f32x4 acc[4][4];
    #pragma unroll
    for (int i = 0; i < 4; i++)
        #pragma unroll
        for (int j = 0; j < 4; j++) acc[i][j] = (f32x4){0.f, 0.f, 0.f, 0.f};

    int srow = lane >> 2;            // 0..15
    int skof = (lane & 3) * 8;       // halves (16 B granules)

#define STAGE(buf, kk) do {                                                   \
        _Pragma("unroll")                                                     \
        for (int q = 0; q < 2; q++) {                                         \
            int rg = wave * 32 + q * 16;                                      \
            size_t ga = (size_t)(row0 + rg + srow) * K + (kk) + skof;         \
            gl_lds16(&X16[ga], &As[buf][rg * BK]);                            \
        } } while (0)

    int nk = K / BK;
    STAGE(0, 0);
    __syncthreads();

    for (int kc = 0; kc < nk; kc++) {
        int cur = kc & 1;
        if (kc + 1 < nk) STAGE(1 - cur, (kc + 1) * BK);

        f16x8 b[4];
        #pragma unroll
        for (int nt = 0; nt < 4; nt++) {
            size_t gb = (size_t)(col0 + wn * 64 + nt * 16 + l16) * K + kc * BK + quad * 8;
            b[nt] = *(const f16x8*)&Wt[gb];
        }
        f16x8 a[4];
        #pragma unroll
        for (int mt = 0; mt < 4; mt++) {
            int r = wm * 64 + mt * 16 + l16;
            a[mt] = *(f16x8*)&As[cur][r * BK + quad * 8];
        }
        #pragma unroll
        for (int mt = 0; mt < 4; mt++)
            #pragma unroll
            for (int nt = 0; nt < 4; nt++)
                acc[mt][nt] = __builtin_amdgcn_mfma_f32_16x16x32_f16(a[mt], b[nt], acc[mt][nt], 0, 0, 0);
        __syncthreads();
    }
#undef STAGE

    // epilogue 1: store H as fp16 (C/D layout col=lane&15, row=quad*4+reg)
    #pragma unroll
    for (int mt = 0; mt < 4; mt++) {
        #pragma unroll
        for (int r = 0; r < 4; r++) {
            int row = row0 + wm*64 + mt*16 + quad*4 + r;
            if (row >= M) continue;
            #pragma unroll
            for (int nt = 0; nt < 4; nt++) {
                size_t idx = (size_t)row * HC + col0 + wn*64 + nt*16 + l16;
                H16out[idx] = f2h(acc[mt][nt][r]);
            }
        }
    }

    // epilogue 2: att score dots; this wave's cols = head (2*by + wn).
    int headw = blockIdx.y * 2 + wn;
    float sS[4], sD[4];
    #pragma unroll
    for (int nt = 0; nt < 4; nt++) {
        sS[nt] = attS[headw * CDIM + nt*16 + l16];
        sD[nt] = attD[headw * CDIM + nt*16 + l16];
    }
    #pragma unroll
    for (int mt = 0; mt < 4; mt++) {
        #pragma unroll
        for (int r = 0; r < 4; r++) {
            float ps = 0.f, pd = 0.f;
            #pragma unroll
            for (int nt = 0; nt < 4; nt++) {
                float av = acc[mt][nt][r];
                ps += av * sS[nt];
                pd += av * sD[nt];
            }
            #pragma unroll
            for (int d = 1; d <= 8; d <<= 1) {
                ps += __shfl_xor(ps, d);
                pd += __shfl_xor(pd, d);
            }
            int row = row0 + wm*64 + mt*16 + quad*4 + r;
            if (l16 == 0 && row < M) {
                a_src_v[row * HEADS + headw] = ps;
                a_dst_v[row * HEADS + headw] = pd;
            }
        }
    }
}

// ---------------- aggregation: softmax + gather (fp16 H, 16 B loads, 32-bit offsets) ----------------
// wave = head; lane = edge_sub(3b) x c8(3b): 8 edges/iter, ushort8 load each.

__global__ __launch_bounds__(256) void k_aggregate(
        const ushort* __restrict__ H16,
        const float* __restrict__ a_src_v, const float* __restrict__ a_dst_v,
        const int* __restrict__ rowptr, const int* __restrict__ csr_src,
        const float* __restrict__ bias,
        float* __restrict__ out_f32,          // nullable
        ushort* __restrict__ out_h16,         // nullable (fp16 for next layer)
        int Nn) {
    int n    = blockIdx.x;
    int t    = threadIdx.x;
    int head = t >> 6;
    int lane = t & 63;
    int beg = rowptr[n], end = rowptr[n + 1];
    int deg = end - beg;                 // random in-edges only
    float adst = a_dst_v[n * HEADS + head];
    float es = a_src_v[n * HEADS + head] + adst;
    es = (es > 0.f) ? es : SLOPE * es;
    float ex_self = __expf(es);

    int sub = lane >> 3;                 // 0..7 edge slot
    int c8  = (lane & 7) * 8;            // channel base (8 ch per lane)
    const char* Hbase = (const char*)H16 + (head * CDIM + c8) * 2;

    float acc[8];
    #pragma unroll
    for (int c = 0; c < 8; c++) acc[c] = 0.f;
    float ssum = 0.f;

    for (int base = 0; base < deg; base += 64) {
        int cnt = min(64, deg - base);
        int   s_l  = 0;
        float ex_l = 0.f;
        if (lane < cnt) {
            s_l = csr_src[beg + base + lane];
            float e = a_src_v[s_l * HEADS + head] + adst;
            e = (e > 0.f) ? e : SLOPE * e;
            ex_l = __expf(e);
            ssum += ex_l;
        }
        int off_l = s_l * (HC * 2);      // 32-bit row byte offset (max 25.7 MB)
        for (int j = 0; j < cnt; j += 8) {
            int   offE = __shfl(off_l, j + sub);
            float aE   = __shfl(ex_l,  j + sub);
            f16x8 hv = *(const f16x8*)(Hbase + offE);
            #pragma unroll
            for (int c = 0; c < 8; c++) acc[c] += aE * (float)hv[c];
        }
    }
    #pragma unroll
    for (int d = 1; d <= 32; d <<= 1) ssum += __shfl_xor(ssum, d);
    ssum += ex_self;
    #pragma unroll
    for (int d = 8; d <= 32; d <<= 1) {
        #pragma unroll
        for (int c = 0; c < 8; c++) acc[c] += __shfl_xor(acc[c], d);
    }
    if (sub == 0) {                      // lanes 0..7 cover the head's 64 channels
        f16x8 us = *(const f16x8*)((const char*)H16 + (size_t)n * (HC * 2) + (head * CDIM + c8) * 2);
        float rden = 1.f / (ssum + 1e-16f);
        float o[8];
        #pragma unroll
        for (int c = 0; c < 8; c++) {
            float bv = bias[head * CDIM + c8 + c];
            o[c] = fmaxf((acc[c] + ex_self * (float)us[c]) * rden + bv, 0.f);
        }
        size_t idx = (size_t)n * HC + head * CDIM + c8;
        if (out_f32) {
            float4 o0 = make_float4(o[0], o[1], o[2], o[3]);
            float4 o1 = make_float4(o[4], o[5], o[6], o[7]);
            *(float4*)&out_f32[idx]     = o0;
            *(float4*)&out_f32[idx + 4] = o1;
        }
        if (out_h16) {
            f16x8 ho;
            #pragma unroll
            for (int c = 0; c < 8; c++) ho[c] = (_Float16)o[c];
            *(f16x8*)&out_h16[idx] = ho;
        }
    }
}

// ---------------- launch ----------------

extern "C" void kernel_launch(void* const* d_in, const int* in_sizes, int n_in,
                              void* d_out, int out_size, void* d_ws, size_t ws_size,
                              hipStream_t stream) {
    const float* x0   = (const float*)d_in[0];
    const int*   eidx = (const int*)d_in[1];
    int Nn = in_sizes[0] / IN0;     // 50000
    int E  = in_sizes[1] / 2;       // 850000
    int E_rand = E - Nn;            // 800000 random edges; self-loops inline
    const int* srcp = eidx;
    const int* dstp = eidx + E;

    const float* Wl[3]    = {(const float*)d_in[2],  (const float*)d_in[6],  (const float*)d_in[10]};
    const float* attS[3]  = {(const float*)d_in[3],  (const float*)d_in[7],  (const float*)d_in[11]};
    const float* attD[3]  = {(const float*)d_in[4],  (const float*)d_in[8],  (const float*)d_in[12]};
    const float* biasl[3] = {(const float*)d_in[5],  (const float*)d_in[9],  (const float*)d_in[13]};
    int Kdims[3] = {IN0, HC, HC};

    // workspace carve
    char* p = (char*)d_ws;
    ushort* h16    = (ushort*)p; p += (size_t)NPAD * HC * sizeof(ushort);
    ushort* X16    = (ushort*)p; p += (size_t)NPAD * HC * sizeof(ushort);
    float*  a_src_v= (float*)p;  p += (size_t)Nn * HEADS * sizeof(float);
    float*  a_dst_v= (float*)p;  p += (size_t)Nn * HEADS * sizeof(float);
    int*    rowptr = (int*)p;    p += (size_t)(Nn + 1) * sizeof(int);
    int*    deg    = (int*)p;    p += (size_t)Nn * sizeof(int);
    int*    cur    = (int*)p;    p += (size_t)Nn * sizeof(int);
    int*    partial= (int*)p;    p += 64 * sizeof(int);
    int*    csr_src= (int*)p;    p += (size_t)E_rand * sizeof(int);
    ushort* Wt[3];
    for (int l = 0; l < 3; l++) {
        Wt[l] = (ushort*)p; p += (size_t)HC * Kdims[l] * sizeof(ushort);
    }

    int NB = (Nn + 1023) / 1024;
    int B0 = (E_rand + 255) / 256;
    int B1 = (Nn * IN0 + 255) / 256;
    int Bprep = B0 + B1 + 128 + 256 + 256;

    hipMemsetAsync(deg, 0, (size_t)Nn * sizeof(int), stream);
    k_prep<<<Bprep, 256, 0, stream>>>(dstp, E_rand, deg,
                                      x0, X16, Nn * IN0,
                                      Wl[0], Wt[0], Wl[1], Wt[1], Wl[2], Wt[2],
                                      B0, B1);
    k_scan_partial<<<NB, 1024, 0, stream>>>(deg, Nn, partial);
    k_scan_final<<<NB, 1024, 0, stream>>>(deg, Nn, partial, NB, rowptr, cur);
    k_scatter<<<(E_rand + 255) / 256, 256, 0, stream>>>(srcp, dstp, E_rand, cur, csr_src);

    for (int l = 0; l < 3; l++) {
        dim3 g((Nn + 127) / 128, HC / 128);
        k_gemm_att<<<g, 256, 0, stream>>>(X16, Wt[l], attS[l], attD[l],
                                          h16, a_src_v, a_dst_v, Nn, Kdims[l]);
        if (l < 2) {
            k_aggregate<<<Nn, 256, 0, stream>>>(h16, a_src_v, a_dst_v, rowptr, csr_src,
                                                biasl[l], nullptr, X16, Nn);
        } else {
            k_aggregate<<<Nn, 256, 0, stream>>>(h16, a_src_v, a_dst_v, rowptr, csr_src,
                                                biasl[l], (float*)d_out, nullptr, Nn);
        }
    }
}

// Round 11
// 532.910 us; speedup vs baseline: 1.0664x; 1.0664x over previous
//
#include <hip/hip_runtime.h>
#include <hip/hip_fp16.h>
#include <math.h>

#define IN0    128
#define HEADS  4
#define CDIM   64
#define HC     256
#define SLOPE  0.2f
#define NPAD   50176   // 392*128, row padding
#define BK     32      // k-chunk (halves) = 64 B

typedef __attribute__((ext_vector_type(8))) _Float16 f16x8;
typedef __attribute__((ext_vector_type(4))) float f32x4;

__device__ __forceinline__ float h2f(ushort u) {
    __half h = *(const __half*)&u;
    return __half2float(h);
}
__device__ __forceinline__ ushort f2h(float f) {
    __half h = __float2half_rn(f);
    return *(ushort*)&h;
}

// ---------------- fused prep: degree + xconv(fp16,chunked) + wconv(fp16,chunked) x3 ----------------
// chunked layout: buf[k/32][row][k%32]

__device__ __forceinline__ void wconv_body(const float* __restrict__ W,
                                           ushort* __restrict__ Wc, int K, int b) {
    int tid = b * 256 + threadIdx.x;     // K*256 threads
    int n = tid & 255;                   // output col (coalesced read)
    int k = tid >> 8;
    if (k >= K) return;
    Wc[(size_t)(k >> 5) * (HC * BK) + n * BK + (k & 31)] = f2h(W[(size_t)k * HC + n]);
}

__global__ __launch_bounds__(256) void k_prep(
        const int* __restrict__ dst_rand, int E_rand, int* __restrict__ deg,
        const float* __restrict__ x0, ushort* __restrict__ Xc, int totalx,
        const float* __restrict__ W0, ushort* __restrict__ Wc0,
        const float* __restrict__ W1, ushort* __restrict__ Wc1,
        const float* __restrict__ W2, ushort* __restrict__ Wc2,
        int B0, int B1) {
    int b = blockIdx.x;
    if (b < B0) {
        int i = b * 256 + threadIdx.x;
        if (i < E_rand) atomicAdd(&deg[dst_rand[i]], 1);
        return;
    }
    b -= B0;
    if (b < B1) {                        // xconv: x0 [N][128] -> Xc [4][NPAD][32]
        int i = b * 256 + threadIdx.x;
        if (i < totalx) {
            int n = i >> 7, k = i & 127;
            Xc[(size_t)(k >> 5) * (NPAD * BK) + n * BK + (k & 31)] = f2h(x0[i]);
        }
        return;
    }
    b -= B1;
    if (b < 128) { wconv_body(W0, Wc0, 128, b); return; }
    b -= 128;
    if (b < 256) { wconv_body(W1, Wc1, 256, b); return; }
    b -= 256;
    wconv_body(W2, Wc2, 256, b);
}

// ---------------- scan ----------------

__global__ __launch_bounds__(1024) void k_scan_partial(const int* __restrict__ deg, int Nn,
                                                       int* __restrict__ partial) {
    __shared__ int smem[1024];
    int tid = threadIdx.x;
    int i = blockIdx.x * 1024 + tid;
    smem[tid] = (i < Nn) ? deg[i] : 0;
    __syncthreads();
    #pragma unroll
    for (int d = 512; d >= 1; d >>= 1) {
        if (tid < d) smem[tid] += smem[tid + d];
        __syncthreads();
    }
    if (tid == 0) partial[blockIdx.x] = smem[0];
}

__global__ __launch_bounds__(1024) void k_scan_final(const int* __restrict__ deg, int Nn,
                                                     const int* __restrict__ partial, int NB,
                                                     int* __restrict__ rowptr,
                                                     int* __restrict__ cur) {
    __shared__ int smem[1024];
    __shared__ int s_off, s_total;
    int tid = threadIdx.x;
    if (tid < 64) {
        int v = (tid < NB) ? partial[tid] : 0;
        int incl = v;
        #pragma unroll
        for (int d = 1; d < 64; d <<= 1) {
            int t = __shfl_up(incl, d);
            if (tid >= d) incl += t;
        }
        if (tid == (int)blockIdx.x) s_off = incl - v;
        if (tid == 63) s_total = incl;
    }
    int i = blockIdx.x * 1024 + tid;
    int v = (i < Nn) ? deg[i] : 0;
    smem[tid] = v;
    __syncthreads();
    #pragma unroll
    for (int d = 1; d < 1024; d <<= 1) {
        int t = 0;
        if (tid >= d) t = smem[tid - d];
        __syncthreads();
        smem[tid] += t;
        __syncthreads();
    }
    if (i < Nn) {
        int e = s_off + smem[tid] - v;
        rowptr[i] = e;
        cur[i] = e;
    }
    if (blockIdx.x == 0 && tid == 0) rowptr[Nn] = s_total;
}

__global__ void k_scatter(const int* __restrict__ src, const int* __restrict__ dst, int E_rand,
                          int* __restrict__ cur, int* __restrict__ csr_src) {
    int i = blockIdx.x * blockDim.x + threadIdx.x;
    if (i < E_rand) {
        int d = dst[i];
        int p = atomicAdd(&cur[d], 1);
        csr_src[p] = src[i];
    }
}

// ---------------- fused GEMM + attention scores (fp16 MFMA, no LDS, chunked operands) ----------------
// Every fragment load: 16 consecutive rows x 64 B = 1 KB contiguous per wave instr.

template<int K>
__global__ __launch_bounds__(256) void k_gemm_att(const ushort* __restrict__ Xc,
                                                  const ushort* __restrict__ Wc,
                                                  const float* __restrict__ attS,
                                                  const float* __restrict__ attD,
                                                  ushort* __restrict__ H16out,
                                                  float* __restrict__ a_src_v,
                                                  float* __restrict__ a_dst_v,
                                                  int M) {
    int row0 = blockIdx.x * 128;
    int col0 = blockIdx.y * 128;
    int t    = threadIdx.x;
    int wave = t >> 6, lane = t & 63;
    int wm = wave & 1, wn = wave >> 1;
    int quad = lane >> 4, l16 = lane & 15;

    f32x4 acc[4][4];
    #pragma unroll
    for (int i = 0; i < 4; i++)
        #pragma unroll
        for (int j = 0; j < 4; j++) acc[i][j] = (f32x4){0.f, 0.f, 0.f, 0.f};

    constexpr int NK = K / BK;
    #pragma unroll
    for (int kc = 0; kc < NK; kc++) {
        f16x8 a[4], b[4];
        #pragma unroll
        for (int mt = 0; mt < 4; mt++) {
            size_t ga = (size_t)kc * (NPAD * BK)
                      + (size_t)(row0 + wm * 64 + mt * 16 + l16) * BK + quad * 8;
            a[mt] = *(const f16x8*)&Xc[ga];
        }
        #pragma unroll
        for (int nt = 0; nt < 4; nt++) {
            size_t gb = (size_t)kc * (HC * BK)
                      + (size_t)(col0 + wn * 64 + nt * 16 + l16) * BK + quad * 8;
            b[nt] = *(const f16x8*)&Wc[gb];
        }
        #pragma unroll
        for (int mt = 0; mt < 4; mt++)
            #pragma unroll
            for (int nt = 0; nt < 4; nt++)
                acc[mt][nt] = __builtin_amdgcn_mfma_f32_16x16x32_f16(a[mt], b[nt], acc[mt][nt], 0, 0, 0);
    }

    // epilogue 1: store H as fp16 (C/D layout col=lane&15, row=quad*4+reg)
    #pragma unroll
    for (int mt = 0; mt < 4; mt++) {
        #pragma unroll
        for (int r = 0; r < 4; r++) {
            int row = row0 + wm*64 + mt*16 + quad*4 + r;
            if (row >= M) continue;
            #pragma unroll
            for (int nt = 0; nt < 4; nt++) {
                size_t idx = (size_t)row * HC + col0 + wn*64 + nt*16 + l16;
                H16out[idx] = f2h(acc[mt][nt][r]);
            }
        }
    }

    // epilogue 2: att score dots; this wave's cols = head (2*by + wn).
    int headw = blockIdx.y * 2 + wn;
    float sS[4], sD[4];
    #pragma unroll
    for (int nt = 0; nt < 4; nt++) {
        sS[nt] = attS[headw * CDIM + nt*16 + l16];
        sD[nt] = attD[headw * CDIM + nt*16 + l16];
    }
    #pragma unroll
    for (int mt = 0; mt < 4; mt++) {
        #pragma unroll
        for (int r = 0; r < 4; r++) {
            float ps = 0.f, pd = 0.f;
            #pragma unroll
            for (int nt = 0; nt < 4; nt++) {
                float av = acc[mt][nt][r];
                ps += av * sS[nt];
                pd += av * sD[nt];
            }
            #pragma unroll
            for (int d = 1; d <= 8; d <<= 1) {
                ps += __shfl_xor(ps, d);
                pd += __shfl_xor(pd, d);
            }
            int row = row0 + wm*64 + mt*16 + quad*4 + r;
            if (l16 == 0 && row < M) {
                a_src_v[row * HEADS + headw] = ps;
                a_dst_v[row * HEADS + headw] = pd;
            }
        }
    }
}

// ---------------- aggregation (round-9 proven shape): softmax + gather fp16, j-step 8 ----------------
// out_h16 (layers 0-1) written in chunked layout for the next GEMM.

__global__ __launch_bounds__(256) void k_aggregate(
        const ushort* __restrict__ H16,
        const float* __restrict__ a_src_v, const float* __restrict__ a_dst_v,
        const int* __restrict__ rowptr, const int* __restrict__ csr_src,
        const float* __restrict__ bias,
        float* __restrict__ out_f32,          // nullable
        ushort* __restrict__ out_h16c,        // nullable (fp16, CHUNKED)
        int Nn) {
    int n    = blockIdx.x;
    int t    = threadIdx.x;
    int head = t >> 6;
    int lane = t & 63;
    int beg = rowptr[n], end = rowptr[n + 1];
    int deg = end - beg;                 // random in-edges only
    float adst = a_dst_v[n * HEADS + head];
    float es = a_src_v[n * HEADS + head] + adst;
    es = (es > 0.f) ? es : SLOPE * es;
    float ex_self = __expf(es);

    int sub = lane >> 4;
    int c4  = (lane & 15) * 4;
    float4 acc = make_float4(0.f, 0.f, 0.f, 0.f);
    float ssum = 0.f;

    for (int base = 0; base < deg; base += 64) {
        int cnt = min(64, deg - base);
        int   s_l  = 0;
        float ex_l = 0.f;
        if (lane < cnt) {
            s_l = csr_src[beg + base + lane];
            float e = a_src_v[s_l * HEADS + head] + adst;
            e = (e > 0.f) ? e : SLOPE * e;
            ex_l = __expf(e);
            ssum += ex_l;
        }
        for (int j = 0; j < cnt; j += 8) {
            int   sA = __shfl(s_l,  j + sub);
            float aA = __shfl(ex_l, j + sub);
            int   sB = __shfl(s_l,  j + 4 + sub);
            float aB = __shfl(ex_l, j + 4 + sub);
            ushort4 uA = *(const ushort4*)&H16[(size_t)sA * HC + head * CDIM + c4];
            ushort4 uB = *(const ushort4*)&H16[(size_t)sB * HC + head * CDIM + c4];
            acc.x += aA * h2f(uA.x); acc.y += aA * h2f(uA.y);
            acc.z += aA * h2f(uA.z); acc.w += aA * h2f(uA.w);
            acc.x += aB * h2f(uB.x); acc.y += aB * h2f(uB.y);
            acc.z += aB * h2f(uB.z); acc.w += aB * h2f(uB.w);
        }
    }
    #pragma unroll
    for (int d = 1; d <= 32; d <<= 1) ssum += __shfl_xor(ssum, d);
    ssum += ex_self;
    #pragma unroll
    for (int d = 16; d <= 32; d <<= 1) {
        acc.x += __shfl_xor(acc.x, d);
        acc.y += __shfl_xor(acc.y, d);
        acc.z += __shfl_xor(acc.z, d);
        acc.w += __shfl_xor(acc.w, d);
    }
    if (sub == 0) {
        ushort4 us = *(const ushort4*)&H16[(size_t)n * HC + head * CDIM + c4];
        float rden = 1.f / (ssum + 1e-16f);
        float4 b = *(const float4*)&bias[head * CDIM + c4];
        float4 o;
        o.x = fmaxf((acc.x + ex_self * h2f(us.x)) * rden + b.x, 0.f);
        o.y = fmaxf((acc.y + ex_self * h2f(us.y)) * rden + b.y, 0.f);
        o.z = fmaxf((acc.z + ex_self * h2f(us.z)) * rden + b.z, 0.f);
        o.w = fmaxf((acc.w + ex_self * h2f(us.w)) * rden + b.w, 0.f);
        if (out_f32) {
            size_t idx = (size_t)n * HC + head * CDIM + c4;
            *(float4*)&out_f32[idx] = o;
        }
        if (out_h16c) {
            int ch = head * CDIM + c4;
            size_t idx = (size_t)(ch >> 5) * (NPAD * BK) + (size_t)n * BK + (ch & 31);
            *(ushort4*)&out_h16c[idx] = make_ushort4(f2h(o.x), f2h(o.y), f2h(o.z), f2h(o.w));
        }
    }
}

// ---------------- launch ----------------

extern "C" void kernel_launch(void* const* d_in, const int* in_sizes, int n_in,
                              void* d_out, int out_size, void* d_ws, size_t ws_size,
                              hipStream_t stream) {
    const float* x0   = (const float*)d_in[0];
    const int*   eidx = (const int*)d_in[1];
    int Nn = in_sizes[0] / IN0;     // 50000
    int E  = in_sizes[1] / 2;       // 850000
    int E_rand = E - Nn;            // 800000 random edges; self-loops inline
    const int* srcp = eidx;
    const int* dstp = eidx + E;

    const float* Wl[3]    = {(const float*)d_in[2],  (const float*)d_in[6],  (const float*)d_in[10]};
    const float* attS[3]  = {(const float*)d_in[3],  (const float*)d_in[7],  (const float*)d_in[11]};
    const float* attD[3]  = {(const float*)d_in[4],  (const float*)d_in[8],  (const float*)d_in[12]};
    const float* biasl[3] = {(const float*)d_in[5],  (const float*)d_in[9],  (const float*)d_in[13]};
    int Kdims[3] = {IN0, HC, HC};

    // workspace carve
    char* p = (char*)d_ws;
    ushort* h16    = (ushort*)p; p += (size_t)NPAD * HC * sizeof(ushort);
    ushort* Xc     = (ushort*)p; p += (size_t)NPAD * HC * sizeof(ushort);   // chunked
    float*  a_src_v= (float*)p;  p += (size_t)Nn * HEADS * sizeof(float);
    float*  a_dst_v= (float*)p;  p += (size_t)Nn * HEADS * sizeof(float);
    int*    rowptr = (int*)p;    p += (size_t)(Nn + 1) * sizeof(int);
    int*    deg    = (int*)p;    p += (size_t)Nn * sizeof(int);
    int*    cur    = (int*)p;    p += (size_t)Nn * sizeof(int);
    int*    partial= (int*)p;    p += 64 * sizeof(int);
    int*    csr_src= (int*)p;    p += (size_t)E_rand * sizeof(int);
    ushort* Wc[3];
    for (int l = 0; l < 3; l++) {
        Wc[l] = (ushort*)p; p += (size_t)HC * Kdims[l] * sizeof(ushort);
    }

    int NB = (Nn + 1023) / 1024;
    int B0 = (E_rand + 255) / 256;
    int B1 = (Nn * IN0 + 255) / 256;
    int Bprep = B0 + B1 + 128 + 256 + 256;

    hipMemsetAsync(deg, 0, (size_t)Nn * sizeof(int), stream);
    k_prep<<<Bprep, 256, 0, stream>>>(dstp, E_rand, deg,
                                      x0, Xc, Nn * IN0,
                                      Wl[0], Wc[0], Wl[1], Wc[1], Wl[2], Wc[2],
                                      B0, B1);
    k_scan_partial<<<NB, 1024, 0, stream>>>(deg, Nn, partial);
    k_scan_final<<<NB, 1024, 0, stream>>>(deg, Nn, partial, NB, rowptr, cur);
    k_scatter<<<(E_rand + 255) / 256, 256, 0, stream>>>(srcp, dstp, E_rand, cur, csr_src);

    dim3 g((Nn + 127) / 128, HC / 128);
    for (int l = 0; l < 3; l++) {
        if (l == 0)
            k_gemm_att<128><<<g, 256, 0, stream>>>(Xc, Wc[l], attS[l], attD[l],
                                                   h16, a_src_v, a_dst_v, Nn);
        else
            k_gemm_att<256><<<g, 256, 0, stream>>>(Xc, Wc[l], attS[l], attD[l],
                                                   h16, a_src_v, a_dst_v, Nn);
        if (l < 2) {
            k_aggregate<<<Nn, 256, 0, stream>>>(h16, a_src_v, a_dst_v, rowptr, csr_src,
                                                biasl[l], nullptr, Xc, Nn);
        } else {
            k_aggregate<<<Nn, 256, 0, stream>>>(h16, a_src_v, a_dst_v, rowptr, csr_src,
                                                biasl[l], (float*)d_out, nullptr, Nn);
        }
    }
}

// Round 12
// 503.199 us; speedup vs baseline: 1.1294x; 1.0590x over previous
//
#include <hip/hip_runtime.h>
#include <hip/hip_fp16.h>
#include <math.h>

#define IN0    128
#define HEADS  4
#define CDIM   64
#define HC     256
#define SLOPE  0.2f
#define NPAD   50176   // 392*128, row padding
#define BK     32      // k-chunk (halves) = 64 B

typedef __attribute__((ext_vector_type(8))) _Float16 f16x8;
typedef __attribute__((ext_vector_type(4))) float f32x4;

__device__ __forceinline__ float h2f(ushort u) {
    __half h = *(const __half*)&u;
    return __half2float(h);
}
__device__ __forceinline__ ushort f2h(float f) {
    __half h = __float2half_rn(f);
    return *(ushort*)&h;
}

// ---------------- fused prep: degree + xconv(fp16,chunked) + wconv(fp16,chunked) x3 ----------------
// chunked layout: buf[k/32][row][k%32]

__device__ __forceinline__ void wconv_body(const float* __restrict__ W,
                                           ushort* __restrict__ Wc, int K, int b) {
    int tid = b * 256 + threadIdx.x;     // K*256 threads
    int n = tid & 255;                   // output col (coalesced read)
    int k = tid >> 8;
    if (k >= K) return;
    Wc[(size_t)(k >> 5) * (HC * BK) + n * BK + (k & 31)] = f2h(W[(size_t)k * HC + n]);
}

__global__ __launch_bounds__(256) void k_prep(
        const int* __restrict__ dst_rand, int E_rand, int* __restrict__ deg,
        const float* __restrict__ x0, ushort* __restrict__ Xc, int totalx,
        const float* __restrict__ W0, ushort* __restrict__ Wc0,
        const float* __restrict__ W1, ushort* __restrict__ Wc1,
        const float* __restrict__ W2, ushort* __restrict__ Wc2,
        int B0, int B1) {
    int b = blockIdx.x;
    if (b < B0) {
        int i = b * 256 + threadIdx.x;
        if (i < E_rand) atomicAdd(&deg[dst_rand[i]], 1);
        return;
    }
    b -= B0;
    if (b < B1) {                        // xconv: x0 [N][128] -> Xc [4][NPAD][32]
        int i = b * 256 + threadIdx.x;
        if (i < totalx) {
            int n = i >> 7, k = i & 127;
            Xc[(size_t)(k >> 5) * (NPAD * BK) + n * BK + (k & 31)] = f2h(x0[i]);
        }
        return;
    }
    b -= B1;
    if (b < 128) { wconv_body(W0, Wc0, 128, b); return; }
    b -= 128;
    if (b < 256) { wconv_body(W1, Wc1, 256, b); return; }
    b -= 256;
    wconv_body(W2, Wc2, 256, b);
}

// ---------------- single-kernel scan (prefix-of-prefixes brute force) ----------------

__global__ __launch_bounds__(1024) void k_scan(const int* __restrict__ deg, int Nn,
                                               int* __restrict__ rowptr,
                                               int* __restrict__ cur) {
    __shared__ int smem[1024];
    int tid = threadIdx.x;
    // phase 0: sum of deg[0 .. blockIdx*1024)
    int pre = 0;
    int limit = blockIdx.x * 1024;
    for (int i = tid; i < limit; i += 1024) pre += deg[i];
    smem[tid] = pre;
    __syncthreads();
    #pragma unroll
    for (int d = 512; d >= 1; d >>= 1) {
        if (tid < d) smem[tid] += smem[tid + d];
        __syncthreads();
    }
    int s_off = smem[0];
    __syncthreads();
    // phase 1: block-local inclusive scan
    int i = blockIdx.x * 1024 + tid;
    int v = (i < Nn) ? deg[i] : 0;
    smem[tid] = v;
    __syncthreads();
    #pragma unroll
    for (int d = 1; d < 1024; d <<= 1) {
        int t = 0;
        if (tid >= d) t = smem[tid - d];
        __syncthreads();
        smem[tid] += t;
        __syncthreads();
    }
    if (i < Nn) {
        int e = s_off + smem[tid] - v;
        rowptr[i] = e;
        cur[i] = e;
    }
    if (blockIdx.x == gridDim.x - 1 && tid == 1023) rowptr[Nn] = s_off + smem[1023];
}

__global__ void k_scatter(const int* __restrict__ src, const int* __restrict__ dst, int E_rand,
                          int* __restrict__ cur, int* __restrict__ csr_src) {
    int i = blockIdx.x * blockDim.x + threadIdx.x;
    if (i < E_rand) {
        int d = dst[i];
        int p = atomicAdd(&cur[d], 1);
        csr_src[p] = src[i];
    }
}

// ---------------- fused GEMM + attention scores (fp16 MFMA, no LDS, chunked operands) ----------------

template<int K>
__global__ __launch_bounds__(256) void k_gemm_att(const ushort* __restrict__ Xc,
                                                  const ushort* __restrict__ Wc,
                                                  const float* __restrict__ attS,
                                                  const float* __restrict__ attD,
                                                  ushort* __restrict__ H16out,
                                                  float* __restrict__ a_src_v,
                                                  float* __restrict__ a_dst_v,
                                                  int M) {
    int row0 = blockIdx.x * 128;
    int col0 = blockIdx.y * 128;
    int t    = threadIdx.x;
    int wave = t >> 6, lane = t & 63;
    int wm = wave & 1, wn = wave >> 1;
    int quad = lane >> 4, l16 = lane & 15;

    f32x4 acc[4][4];
    #pragma unroll
    for (int i = 0; i < 4; i++)
        #pragma unroll
        for (int j = 0; j < 4; j++) acc[i][j] = (f32x4){0.f, 0.f, 0.f, 0.f};

    constexpr int NK = K / BK;
    #pragma unroll
    for (int kc = 0; kc < NK; kc++) {
        f16x8 a[4], b[4];
        #pragma unroll
        for (int mt = 0; mt < 4; mt++) {
            size_t ga = (size_t)kc * (NPAD * BK)
                      + (size_t)(row0 + wm * 64 + mt * 16 + l16) * BK + quad * 8;
            a[mt] = *(const f16x8*)&Xc[ga];
        }
        #pragma unroll
        for (int nt = 0; nt < 4; nt++) {
            size_t gb = (size_t)kc * (HC * BK)
                      + (size_t)(col0 + wn * 64 + nt * 16 + l16) * BK + quad * 8;
            b[nt] = *(const f16x8*)&Wc[gb];
        }
        #pragma unroll
        for (int mt = 0; mt < 4; mt++)
            #pragma unroll
            for (int nt = 0; nt < 4; nt++)
                acc[mt][nt] = __builtin_amdgcn_mfma_f32_16x16x32_f16(a[mt], b[nt], acc[mt][nt], 0, 0, 0);
    }

    // epilogue 1: store H as fp16 (C/D layout col=lane&15, row=quad*4+reg)
    #pragma unroll
    for (int mt = 0; mt < 4; mt++) {
        #pragma unroll
        for (int r = 0; r < 4; r++) {
            int row = row0 + wm*64 + mt*16 + quad*4 + r;
            if (row >= M) continue;
            #pragma unroll
            for (int nt = 0; nt < 4; nt++) {
                size_t idx = (size_t)row * HC + col0 + wn*64 + nt*16 + l16;
                H16out[idx] = f2h(acc[mt][nt][r]);
            }
        }
    }

    // epilogue 2: att score dots; this wave's cols = head (2*by + wn).
    int headw = blockIdx.y * 2 + wn;
    float sS[4], sD[4];
    #pragma unroll
    for (int nt = 0; nt < 4; nt++) {
        sS[nt] = attS[headw * CDIM + nt*16 + l16];
        sD[nt] = attD[headw * CDIM + nt*16 + l16];
    }
    #pragma unroll
    for (int mt = 0; mt < 4; mt++) {
        #pragma unroll
        for (int r = 0; r < 4; r++) {
            float ps = 0.f, pd = 0.f;
            #pragma unroll
            for (int nt = 0; nt < 4; nt++) {
                float av = acc[mt][nt][r];
                ps += av * sS[nt];
                pd += av * sD[nt];
            }
            #pragma unroll
            for (int d = 1; d <= 8; d <<= 1) {
                ps += __shfl_xor(ps, d);
                pd += __shfl_xor(pd, d);
            }
            int row = row0 + wm*64 + mt*16 + quad*4 + r;
            if (l16 == 0 && row < M) {
                a_src_v[row * HEADS + headw] = ps;
                a_dst_v[row * HEADS + headw] = pd;
            }
        }
    }
}

// ---------------- aggregation: ONE WAVE PER NODE, all 4 heads in-wave ----------------
// ex phase: lane = eslot(4b) x head(2b) covers 16 edges x 4 heads.
// acc phase: lane = head(2b) x c4(4b); per edge one 8B/lane load = full 512B row.
// No cross-lane acc reduction needed.

__global__ __launch_bounds__(256) void k_aggregate(
        const ushort* __restrict__ H16,
        const float* __restrict__ a_src_v, const float* __restrict__ a_dst_v,
        const int* __restrict__ rowptr, const int* __restrict__ csr_src,
        const float* __restrict__ bias,
        float* __restrict__ out_f32,          // nullable
        ushort* __restrict__ out_h16c,        // nullable (fp16, CHUNKED)
        int Nn) {
    int wave = threadIdx.x >> 6;
    int lane = threadIdx.x & 63;
    int n = blockIdx.x * 4 + wave;
    if (n >= Nn) return;

    int e16 = lane >> 2;        // edge slot (ex phase)
    int hs  = lane & 3;         // head (ex phase)
    int ha  = lane >> 4;        // head (acc phase)
    int c4  = (lane & 15) * 4;  // channel base (acc phase)

    int beg = rowptr[n], end = rowptr[n + 1];
    int deg = end - beg;
    float adst_s = a_dst_v[n * HEADS + hs];
    float es = a_src_v[n * HEADS + hs] + adst_s;
    es = (es > 0.f) ? es : SLOPE * es;
    float ex_self_s = __expf(es);

    float ssum = 0.f;
    float4 acc = make_float4(0.f, 0.f, 0.f, 0.f);
    const char* Hb = (const char*)H16 + (ha * CDIM + c4) * 2;

    for (int base = 0; base < deg; base += 16) {
        int cnt = min(16, deg - base);
        int s_l = 0; float ex_l = 0.f;
        if (e16 < cnt) {
            s_l = csr_src[beg + base + e16];
            float e = a_src_v[s_l * HEADS + hs] + adst_s;
            e = (e > 0.f) ? e : SLOPE * e;
            ex_l = __expf(e);
            ssum += ex_l;
        }
        int off_l = s_l * (HC * 2);   // 32-bit row byte offset
        #pragma unroll 2
        for (int j = 0; j < cnt; j++) {
            int   srcl = j * 4 + ha;
            float aE = __shfl(ex_l,  srcl);
            int   oE = __shfl(off_l, srcl);
            ushort4 u = *(const ushort4*)(Hb + oE);
            acc.x += aE * h2f(u.x); acc.y += aE * h2f(u.y);
            acc.z += aE * h2f(u.z); acc.w += aE * h2f(u.w);
        }
    }
    // denom: reduce over edge slots (xor bits 2..5); heads preserved in bits 0-1
    #pragma unroll
    for (int d = 4; d <= 32; d <<= 1) ssum += __shfl_xor(ssum, d);
    ssum += ex_self_s;                       // lane holds denom for head hs
    float den_a = __shfl(ssum, ha);          // lane ha has hs == ha
    float exs_a = __shfl(ex_self_s, ha);

    ushort4 us = *(const ushort4*)((const char*)H16 + (size_t)n * (HC * 2) + (ha * CDIM + c4) * 2);
    float rden = 1.f / (den_a + 1e-16f);
    float4 b = *(const float4*)&bias[ha * CDIM + c4];
    float4 o;
    o.x = fmaxf((acc.x + exs_a * h2f(us.x)) * rden + b.x, 0.f);
    o.y = fmaxf((acc.y + exs_a * h2f(us.y)) * rden + b.y, 0.f);
    o.z = fmaxf((acc.z + exs_a * h2f(us.z)) * rden + b.z, 0.f);
    o.w = fmaxf((acc.w + exs_a * h2f(us.w)) * rden + b.w, 0.f);

    if (out_f32) {
        *(float4*)&out_f32[(size_t)n * HC + ha * CDIM + c4] = o;
    }
    if (out_h16c) {
        int ch = ha * CDIM + c4;
        size_t idx = (size_t)(ch >> 5) * (NPAD * BK) + (size_t)n * BK + (ch & 31);
        *(ushort4*)&out_h16c[idx] = make_ushort4(f2h(o.x), f2h(o.y), f2h(o.z), f2h(o.w));
    }
}

// ---------------- launch ----------------

extern "C" void kernel_launch(void* const* d_in, const int* in_sizes, int n_in,
                              void* d_out, int out_size, void* d_ws, size_t ws_size,
                              hipStream_t stream) {
    const float* x0   = (const float*)d_in[0];
    const int*   eidx = (const int*)d_in[1];
    int Nn = in_sizes[0] / IN0;     // 50000
    int E  = in_sizes[1] / 2;       // 850000
    int E_rand = E - Nn;            // 800000 random edges; self-loops inline
    const int* srcp = eidx;
    const int* dstp = eidx + E;

    const float* Wl[3]    = {(const float*)d_in[2],  (const float*)d_in[6],  (const float*)d_in[10]};
    const float* attS[3]  = {(const float*)d_in[3],  (const float*)d_in[7],  (const float*)d_in[11]};
    const float* attD[3]  = {(const float*)d_in[4],  (const float*)d_in[8],  (const float*)d_in[12]};
    const float* biasl[3] = {(const float*)d_in[5],  (const float*)d_in[9],  (const float*)d_in[13]};
    int Kdims[3] = {IN0, HC, HC};

    // workspace carve
    char* p = (char*)d_ws;
    ushort* h16    = (ushort*)p; p += (size_t)NPAD * HC * sizeof(ushort);
    ushort* Xc     = (ushort*)p; p += (size_t)NPAD * HC * sizeof(ushort);   // chunked
    float*  a_src_v= (float*)p;  p += (size_t)Nn * HEADS * sizeof(float);
    float*  a_dst_v= (float*)p;  p += (size_t)Nn * HEADS * sizeof(float);
    int*    rowptr = (int*)p;    p += (size_t)(Nn + 1) * sizeof(int);
    int*    deg    = (int*)p;    p += (size_t)Nn * sizeof(int);
    int*    cur    = (int*)p;    p += (size_t)Nn * sizeof(int);
    int*    csr_src= (int*)p;    p += (size_t)E_rand * sizeof(int);
    ushort* Wc[3];
    for (int l = 0; l < 3; l++) {
        Wc[l] = (ushort*)p; p += (size_t)HC * Kdims[l] * sizeof(ushort);
    }

    int NB = (Nn + 1023) / 1024;
    int B0 = (E_rand + 255) / 256;
    int B1 = (Nn * IN0 + 255) / 256;
    int Bprep = B0 + B1 + 128 + 256 + 256;

    hipMemsetAsync(deg, 0, (size_t)Nn * sizeof(int), stream);
    k_prep<<<Bprep, 256, 0, stream>>>(dstp, E_rand, deg,
                                      x0, Xc, Nn * IN0,
                                      Wl[0], Wc[0], Wl[1], Wc[1], Wl[2], Wc[2],
                                      B0, B1);
    k_scan<<<NB, 1024, 0, stream>>>(deg, Nn, rowptr, cur);
    k_scatter<<<(E_rand + 255) / 256, 256, 0, stream>>>(srcp, dstp, E_rand, cur, csr_src);

    dim3 g((Nn + 127) / 128, HC / 128);
    dim3 ga((Nn + 3) / 4);
    for (int l = 0; l < 3; l++) {
        if (l == 0)
            k_gemm_att<128><<<g, 256, 0, stream>>>(Xc, Wc[l], attS[l], attD[l],
                                                   h16, a_src_v, a_dst_v, Nn);
        else
            k_gemm_att<256><<<g, 256, 0, stream>>>(Xc, Wc[l], attS[l], attD[l],
                                                   h16, a_src_v, a_dst_v, Nn);
        if (l < 2) {
            k_aggregate<<<ga, 256, 0, stream>>>(h16, a_src_v, a_dst_v, rowptr, csr_src,
                                                biasl[l], nullptr, Xc, Nn);
        } else {
            k_aggregate<<<ga, 256, 0, stream>>>(h16, a_src_v, a_dst_v, rowptr, csr_src,
                                                biasl[l], (float*)d_out, nullptr, Nn);
        }
    }
}

// Round 13
// 475.833 us; speedup vs baseline: 1.1943x; 1.0575x over previous
//
#include <hip/hip_runtime.h>
#include <hip/hip_fp16.h>
#include <math.h>

#define IN0    128
#define HEADS  4
#define CDIM   64
#define HC     256
#define SLOPE  0.2f
#define NPAD   50176   // 392*128, row padding
#define BK     32      // k-chunk (halves) = 64 B

typedef __attribute__((ext_vector_type(8))) _Float16 f16x8;
typedef __attribute__((ext_vector_type(4))) float f32x4;

__device__ __forceinline__ float h2f(ushort u) {
    __half h = *(const __half*)&u;
    return __half2float(h);
}
__device__ __forceinline__ ushort f2h(float f) {
    __half h = __float2half_rn(f);
    return *(ushort*)&h;
}

// ---------------- fused prep: degree + xconv(fp16,chunked) + wconv(fp16,chunked) x3 ----------------

__device__ __forceinline__ void wconv_body(const float* __restrict__ W,
                                           ushort* __restrict__ Wc, int K, int b) {
    int tid = b * 256 + threadIdx.x;     // K*256 threads
    int n = tid & 255;                   // output col (coalesced read)
    int k = tid >> 8;
    if (k >= K) return;
    Wc[(size_t)(k >> 5) * (HC * BK) + n * BK + (k & 31)] = f2h(W[(size_t)k * HC + n]);
}

__global__ __launch_bounds__(256) void k_prep(
        const int* __restrict__ dst_rand, int E_rand, int* __restrict__ deg,
        const float* __restrict__ x0, ushort* __restrict__ Xc, int totalx,
        const float* __restrict__ W0, ushort* __restrict__ Wc0,
        const float* __restrict__ W1, ushort* __restrict__ Wc1,
        const float* __restrict__ W2, ushort* __restrict__ Wc2,
        int B0, int B1) {
    int b = blockIdx.x;
    if (b < B0) {
        int i = b * 256 + threadIdx.x;
        if (i < E_rand) atomicAdd(&deg[dst_rand[i]], 1);
        return;
    }
    b -= B0;
    if (b < B1) {                        // xconv: x0 [N][128] -> Xc [4][NPAD][32]
        int i = b * 256 + threadIdx.x;
        if (i < totalx) {
            int n = i >> 7, k = i & 127;
            Xc[(size_t)(k >> 5) * (NPAD * BK) + n * BK + (k & 31)] = f2h(x0[i]);
        }
        return;
    }
    b -= B1;
    if (b < 128) { wconv_body(W0, Wc0, 128, b); return; }
    b -= 128;
    if (b < 256) { wconv_body(W1, Wc1, 256, b); return; }
    b -= 256;
    wconv_body(W2, Wc2, 256, b);
}

// ---------------- single-kernel scan (prefix-of-prefixes brute force) ----------------

__global__ __launch_bounds__(1024) void k_scan(const int* __restrict__ deg, int Nn,
                                               int* __restrict__ rowptr,
                                               int* __restrict__ cur) {
    __shared__ int smem[1024];
    int tid = threadIdx.x;
    int pre = 0;
    int limit = blockIdx.x * 1024;
    for (int i = tid; i < limit; i += 1024) pre += deg[i];
    smem[tid] = pre;
    __syncthreads();
    #pragma unroll
    for (int d = 512; d >= 1; d >>= 1) {
        if (tid < d) smem[tid] += smem[tid + d];
        __syncthreads();
    }
    int s_off = smem[0];
    __syncthreads();
    int i = blockIdx.x * 1024 + tid;
    int v = (i < Nn) ? deg[i] : 0;
    smem[tid] = v;
    __syncthreads();
    #pragma unroll
    for (int d = 1; d < 1024; d <<= 1) {
        int t = 0;
        if (tid >= d) t = smem[tid - d];
        __syncthreads();
        smem[tid] += t;
        __syncthreads();
    }
    if (i < Nn) {
        int e = s_off + smem[tid] - v;
        rowptr[i] = e;
        cur[i] = e;
    }
    if (blockIdx.x == gridDim.x - 1 && tid == 1023) rowptr[Nn] = s_off + smem[1023];
}

__global__ void k_scatter(const int* __restrict__ src, const int* __restrict__ dst, int E_rand,
                          int* __restrict__ cur, int* __restrict__ csr_src) {
    int i = blockIdx.x * blockDim.x + threadIdx.x;
    if (i < E_rand) {
        int d = dst[i];
        int p = atomicAdd(&cur[d], 1);
        csr_src[p] = src[i];
    }
}

// ---------------- fused GEMM + attention scores (fp16 MFMA, no LDS, chunked operands) ----------------
// Grid: 784 linear = 49 groups x 16; siblings (same rows, both col-halves) placed 8 apart
// so they land on the same XCD (id%8 round-robin) and share X rows in L2.

template<int K>
__global__ __launch_bounds__(256) void k_gemm_att(const ushort* __restrict__ Xc,
                                                  const ushort* __restrict__ Wc,
                                                  const float* __restrict__ attS,
                                                  const float* __restrict__ attD,
                                                  ushort* __restrict__ H16out,
                                                  float* __restrict__ a_src_v,
                                                  float* __restrict__ a_dst_v,
                                                  int M) {
    int id    = blockIdx.x;
    int group = id >> 4;
    int sub   = id & 15;
    int row0  = (group * 8 + (sub & 7)) * 128;
    int colb  = sub >> 3;
    int col0  = colb * 128;

    int t    = threadIdx.x;
    int wave = t >> 6, lane = t & 63;
    int wm = wave & 1, wn = wave >> 1;
    int quad = lane >> 4, l16 = lane & 15;

    f32x4 acc[4][4];
    #pragma unroll
    for (int i = 0; i < 4; i++)
        #pragma unroll
        for (int j = 0; j < 4; j++) acc[i][j] = (f32x4){0.f, 0.f, 0.f, 0.f};

    constexpr int NK = K / BK;
    #pragma unroll
    for (int kc = 0; kc < NK; kc++) {
        f16x8 a[4], b[4];
        #pragma unroll
        for (int mt = 0; mt < 4; mt++) {
            size_t ga = (size_t)kc * (NPAD * BK)
                      + (size_t)(row0 + wm * 64 + mt * 16 + l16) * BK + quad * 8;
            a[mt] = *(const f16x8*)&Xc[ga];
        }
        #pragma unroll
        for (int nt = 0; nt < 4; nt++) {
            size_t gb = (size_t)kc * (HC * BK)
                      + (size_t)(col0 + wn * 64 + nt * 16 + l16) * BK + quad * 8;
            b[nt] = *(const f16x8*)&Wc[gb];
        }
        #pragma unroll
        for (int mt = 0; mt < 4; mt++)
            #pragma unroll
            for (int nt = 0; nt < 4; nt++)
                acc[mt][nt] = __builtin_amdgcn_mfma_f32_16x16x32_f16(a[mt], b[nt], acc[mt][nt], 0, 0, 0);
    }

    // epilogue 1: store H as fp16 (C/D layout col=lane&15, row=quad*4+reg)
    #pragma unroll
    for (int mt = 0; mt < 4; mt++) {
        #pragma unroll
        for (int r = 0; r < 4; r++) {
            int row = row0 + wm*64 + mt*16 + quad*4 + r;
            if (row >= M) continue;
            #pragma unroll
            for (int nt = 0; nt < 4; nt++) {
                size_t idx = (size_t)row * HC + col0 + wn*64 + nt*16 + l16;
                H16out[idx] = f2h(acc[mt][nt][r]);
            }
        }
    }

    // epilogue 2: att score dots; this wave's cols = head (2*colb + wn).
    int headw = colb * 2 + wn;
    float sS[4], sD[4];
    #pragma unroll
    for (int nt = 0; nt < 4; nt++) {
        sS[nt] = attS[headw * CDIM + nt*16 + l16];
        sD[nt] = attD[headw * CDIM + nt*16 + l16];
    }
    #pragma unroll
    for (int mt = 0; mt < 4; mt++) {
        #pragma unroll
        for (int r = 0; r < 4; r++) {
            float ps = 0.f, pd = 0.f;
            #pragma unroll
            for (int nt = 0; nt < 4; nt++) {
                float av = acc[mt][nt][r];
                ps += av * sS[nt];
                pd += av * sD[nt];
            }
            #pragma unroll
            for (int d = 1; d <= 8; d <<= 1) {
                ps += __shfl_xor(ps, d);
                pd += __shfl_xor(pd, d);
            }
            int row = row0 + wm*64 + mt*16 + quad*4 + r;
            if (l16 == 0 && row < M) {
                a_src_v[row * HEADS + headw] = ps;
                a_dst_v[row * HEADS + headw] = pd;
            }
        }
    }
}

// ---------------- aggregation: one wave per node, 4 heads in-wave, 4-deep gather unroll ----------------

__global__ __launch_bounds__(256) void k_aggregate(
        const ushort* __restrict__ H16,
        const float* __restrict__ a_src_v, const float* __restrict__ a_dst_v,
        const int* __restrict__ rowptr, const int* __restrict__ csr_src,
        const float* __restrict__ bias,
        float* __restrict__ out_f32,          // nullable
        ushort* __restrict__ out_h16c,        // nullable (fp16, CHUNKED)
        int Nn) {
    int wave = threadIdx.x >> 6;
    int lane = threadIdx.x & 63;
    int n = blockIdx.x * 4 + wave;
    if (n >= Nn) return;

    int e16 = lane >> 2;        // edge slot (ex phase)
    int hs  = lane & 3;         // head (ex phase)
    int ha  = lane >> 4;        // head (acc phase)
    int c4  = (lane & 15) * 4;  // channel base (acc phase)

    int beg = rowptr[n], end = rowptr[n + 1];
    int deg = end - beg;
    float adst_s = a_dst_v[n * HEADS + hs];
    float es = a_src_v[n * HEADS + hs] + adst_s;
    es = (es > 0.f) ? es : SLOPE * es;
    float ex_self_s = __expf(es);

    float ssum = 0.f;
    float4 acc = make_float4(0.f, 0.f, 0.f, 0.f);
    const char* Hb = (const char*)H16 + (ha * CDIM + c4) * 2;

    for (int base = 0; base < deg; base += 16) {
        int cnt = min(16, deg - base);
        int s_l = 0; float ex_l = 0.f;
        if (e16 < cnt) {
            s_l = csr_src[beg + base + e16];
            float e = a_src_v[s_l * HEADS + hs] + adst_s;
            e = (e > 0.f) ? e : SLOPE * e;
            ex_l = __expf(e);
            ssum += ex_l;
        }
        int off_l = s_l * (HC * 2);   // 32-bit row byte offset
        int cnt4 = (cnt + 3) & ~3;    // OOB slots: ex=0, off=0 (harmless L1-hot load)
        for (int j = 0; j < cnt4; j += 4) {
            float a0 = __shfl(ex_l,  (j + 0) * 4 + ha);
            int   o0 = __shfl(off_l, (j + 0) * 4 + ha);
            float a1 = __shfl(ex_l,  (j + 1) * 4 + ha);
            int   o1 = __shfl(off_l, (j + 1) * 4 + ha);
            float a2 = __shfl(ex_l,  (j + 2) * 4 + ha);
            int   o2 = __shfl(off_l, (j + 2) * 4 + ha);
            float a3 = __shfl(ex_l,  (j + 3) * 4 + ha);
            int   o3 = __shfl(off_l, (j + 3) * 4 + ha);
            ushort4 u0 = *(const ushort4*)(Hb + o0);
            ushort4 u1 = *(const ushort4*)(Hb + o1);
            ushort4 u2 = *(const ushort4*)(Hb + o2);
            ushort4 u3 = *(const ushort4*)(Hb + o3);
            acc.x += a0 * h2f(u0.x); acc.y += a0 * h2f(u0.y);
            acc.z += a0 * h2f(u0.z); acc.w += a0 * h2f(u0.w);
            acc.x += a1 * h2f(u1.x); acc.y += a1 * h2f(u1.y);
            acc.z += a1 * h2f(u1.z); acc.w += a1 * h2f(u1.w);
            acc.x += a2 * h2f(u2.x); acc.y += a2 * h2f(u2.y);
            acc.z += a2 * h2f(u2.z); acc.w += a2 * h2f(u2.w);
            acc.x += a3 * h2f(u3.x); acc.y += a3 * h2f(u3.y);
            acc.z += a3 * h2f(u3.z); acc.w += a3 * h2f(u3.w);
        }
    }
    // denom: reduce over edge slots (xor bits 2..5); heads preserved in bits 0-1
    #pragma unroll
    for (int d = 4; d <= 32; d <<= 1) ssum += __shfl_xor(ssum, d);
    ssum += ex_self_s;
    float den_a = __shfl(ssum, ha);
    float exs_a = __shfl(ex_self_s, ha);

    ushort4 us = *(const ushort4*)((const char*)H16 + (size_t)n * (HC * 2) + (ha * CDIM + c4) * 2);
    float rden = 1.f / (den_a + 1e-16f);
    float4 b = *(const float4*)&bias[ha * CDIM + c4];
    float4 o;
    o.x = fmaxf((acc.x + exs_a * h2f(us.x)) * rden + b.x, 0.f);
    o.y = fmaxf((acc.y + exs_a * h2f(us.y)) * rden + b.y, 0.f);
    o.z = fmaxf((acc.z + exs_a * h2f(us.z)) * rden + b.z, 0.f);
    o.w = fmaxf((acc.w + exs_a * h2f(us.w)) * rden + b.w, 0.f);

    if (out_f32) {
        *(float4*)&out_f32[(size_t)n * HC + ha * CDIM + c4] = o;
    }
    if (out_h16c) {
        int ch = ha * CDIM + c4;
        size_t idx = (size_t)(ch >> 5) * (NPAD * BK) + (size_t)n * BK + (ch & 31);
        *(ushort4*)&out_h16c[idx] = make_ushort4(f2h(o.x), f2h(o.y), f2h(o.z), f2h(o.w));
    }
}

// ---------------- launch ----------------

extern "C" void kernel_launch(void* const* d_in, const int* in_sizes, int n_in,
                              void* d_out, int out_size, void* d_ws, size_t ws_size,
                              hipStream_t stream) {
    const float* x0   = (const float*)d_in[0];
    const int*   eidx = (const int*)d_in[1];
    int Nn = in_sizes[0] / IN0;     // 50000
    int E  = in_sizes[1] / 2;       // 850000
    int E_rand = E - Nn;            // 800000 random edges; self-loops inline
    const int* srcp = eidx;
    const int* dstp = eidx + E;

    const float* Wl[3]    = {(const float*)d_in[2],  (const float*)d_in[6],  (const float*)d_in[10]};
    const float* attS[3]  = {(const float*)d_in[3],  (const float*)d_in[7],  (const float*)d_in[11]};
    const float* attD[3]  = {(const float*)d_in[4],  (const float*)d_in[8],  (const float*)d_in[12]};
    const float* biasl[3] = {(const float*)d_in[5],  (const float*)d_in[9],  (const float*)d_in[13]};
    int Kdims[3] = {IN0, HC, HC};

    // workspace carve
    char* p = (char*)d_ws;
    ushort* h16    = (ushort*)p; p += (size_t)NPAD * HC * sizeof(ushort);
    ushort* Xc     = (ushort*)p; p += (size_t)NPAD * HC * sizeof(ushort);   // chunked
    float*  a_src_v= (float*)p;  p += (size_t)Nn * HEADS * sizeof(float);
    float*  a_dst_v= (float*)p;  p += (size_t)Nn * HEADS * sizeof(float);
    int*    rowptr = (int*)p;    p += (size_t)(Nn + 1) * sizeof(int);
    int*    deg    = (int*)p;    p += (size_t)Nn * sizeof(int);
    int*    cur    = (int*)p;    p += (size_t)Nn * sizeof(int);
    int*    csr_src= (int*)p;    p += (size_t)E_rand * sizeof(int);
    ushort* Wc[3];
    for (int l = 0; l < 3; l++) {
        Wc[l] = (ushort*)p; p += (size_t)HC * Kdims[l] * sizeof(ushort);
    }

    int NB = (Nn + 1023) / 1024;
    int B0 = (E_rand + 255) / 256;
    int B1 = (Nn * IN0 + 255) / 256;
    int Bprep = B0 + B1 + 128 + 256 + 256;

    hipMemsetAsync(deg, 0, (size_t)Nn * sizeof(int), stream);
    k_prep<<<Bprep, 256, 0, stream>>>(dstp, E_rand, deg,
                                      x0, Xc, Nn * IN0,
                                      Wl[0], Wc[0], Wl[1], Wc[1], Wl[2], Wc[2],
                                      B0, B1);
    k_scan<<<NB, 1024, 0, stream>>>(deg, Nn, rowptr, cur);
    k_scatter<<<(E_rand + 255) / 256, 256, 0, stream>>>(srcp, dstp, E_rand, cur, csr_src);

    dim3 g(784);                 // 49 groups x (8 row-blocks x 2 col-blocks), XCD-swizzled
    dim3 ga((Nn + 3) / 4);
    for (int l = 0; l < 3; l++) {
        if (l == 0)
            k_gemm_att<128><<<g, 256, 0, stream>>>(Xc, Wc[l], attS[l], attD[l],
                                                   h16, a_src_v, a_dst_v, Nn);
        else
            k_gemm_att<256><<<g, 256, 0, stream>>>(Xc, Wc[l], attS[l], attD[l],
                                                   h16, a_src_v, a_dst_v, Nn);
        if (l < 2) {
            k_aggregate<<<ga, 256, 0, stream>>>(h16, a_src_v, a_dst_v, rowptr, csr_src,
                                                biasl[l], nullptr, Xc, Nn);
        } else {
            k_aggregate<<<ga, 256, 0, stream>>>(h16, a_src_v, a_dst_v, rowptr, csr_src,
                                                biasl[l], (float*)d_out, nullptr, Nn);
        }
    }
}